// Round 4
// baseline (144.281 us; speedup 1.0000x reference)
//
#include <hip/hip_runtime.h>
#include <hip/hip_bf16.h>
#include <cstdint>

// Problem: B=32, S=1024, H_IN=1024, H=1024
// scores[b,s] = sum_h tanh( enc[b,s,:]·W1_enc[h,:] + hidden[b,:]·W1_hid[h,:] + b1[h] ) * W2[h]
// out[b,0,s] = softmax_s( mask ? -inf : scores )    (b2 is softmax-shift-invariant)
//
// Pipeline: idx_k (mask compaction) -> conv_k (gather+bf16, PRE-SWIZZLED) ->
// pack_k (W1_enc bf16, PRE-SWIZZLED) -> hv_k -> gemm_r (T2 swizzle + T3-minimal
// 2-phase dbuf, BM=128 BN=256 BK=64, 512 thr) -> softmax_k.
//
// LDS swizzle (T2, rule 21 both-sides): 16B chunk c within a row's 8-chunk
// K-segment lives at physical c ^ (row&7). Sources (encC, Wb) are stored
// pre-swizzled by conv_k/pack_k, global_load_lds stays linear, ds_read XORs.

#define BM 128
#define BN 256
#define BK 64

typedef short  s16x8 __attribute__((ext_vector_type(8)));
typedef float  f32x4 __attribute__((ext_vector_type(4)));
typedef unsigned int u32;
typedef unsigned short u16;
typedef unsigned long long u64;

__device__ static inline u32 f2bf(float f) {            // f32 -> bf16 (RNE)
    u32 u = __float_as_uint(f);
    return (u + 0x7fffu + ((u >> 16) & 1u)) >> 16;
}
__device__ static inline u32 pk2(float a, float b) {
    return f2bf(a) | (f2bf(b) << 16);
}

__device__ static inline void gload_lds16(const void* g, void* l) {
    __builtin_amdgcn_global_load_lds(
        (const __attribute__((address_space(1))) u32*)g,
        (__attribute__((address_space(3))) u32*)l, 16, 0, 0);
}

// ---------------- pack W1_enc to bf16, swizzled: chunk gc -> (gc&~7)|((gc&7)^(n&7)) ----------------
__global__ __launch_bounds__(256) void pack_k(const float* __restrict__ W1, u16* __restrict__ Wb) {
    const int i = blockIdx.x * 256 + threadIdx.x;      // 16B-chunk id, 0..131071
    const int n = i >> 7, gc = i & 127;
    const int p = (gc & ~7) | ((gc & 7) ^ (n & 7));
    const float4 v0 = *(const float4*)(W1 + (size_t)n * 2048 + gc * 8);
    const float4 v1 = *(const float4*)(W1 + (size_t)n * 2048 + gc * 8 + 4);
    uint4 o; o.x = pk2(v0.x, v0.y); o.y = pk2(v0.z, v0.w);
    o.z = pk2(v1.x, v1.y); o.w = pk2(v1.z, v1.w);
    *(uint4*)(Wb + (size_t)n * 1024 + p * 8) = o;
}

// ---------------- hv[b][h] = hidden[b,:]·W1_hid[h,:] + b1[h]  (f32, exact) ----------------
__global__ __launch_bounds__(256) void hv_k(const float* __restrict__ hidden,
                                            const float* __restrict__ W1,
                                            const float* __restrict__ b1,
                                            float* __restrict__ hv) {
    const int wid = threadIdx.x >> 6, lane = threadIdx.x & 63;
    const int h = blockIdx.x * 4 + wid;
    const float4* wrow = (const float4*)(W1 + (size_t)h * 2048 + 1024);
    float4 w[4];
#pragma unroll
    for (int q = 0; q < 4; q++) w[q] = wrow[lane + 64 * q];
    for (int b = 0; b < 32; b++) {
        const float4* hb = (const float4*)(hidden + (size_t)b * 1024);
        float p = 0.f;
#pragma unroll
        for (int q = 0; q < 4; q++) {
            float4 x = hb[lane + 64 * q];
            p = fmaf(w[q].x, x.x, fmaf(w[q].y, x.y, fmaf(w[q].z, x.z, fmaf(w[q].w, x.w, p))));
        }
#pragma unroll
        for (int off = 1; off < 64; off <<= 1) p += __shfl_xor(p, off);
        if (lane == 0) hv[(size_t)b * 1024 + h] = p + b1[h];
    }
}

// ---------------- mask dtype detect + per-batch stable compaction ----------------
__global__ __launch_bounds__(256) void idx_k(const void* __restrict__ maskv,
                                             int* __restrict__ sidx,   // [32][1024]
                                             int* __restrict__ cnt) {  // [32]
    const int t = threadIdx.x, wid = t >> 6, lane = t & 63;
    const u32* mw = (const u32*)maskv;
    int f = 0;
#pragma unroll
    for (int j = 0; j < 32; j++) f |= (mw[t * 32 + j] > 1u) ? 1 : 0;
    __shared__ int sflag[4];
    const int anyf = __any(f);
    if (lane == 0) sflag[wid] = anyf;
    __syncthreads();
    const int bytemode = sflag[0] | sflag[1] | sflag[2] | sflag[3];

    const int b = blockIdx.x * 4 + wid;
    int base = 0;
    for (int c = 0; c < 16; c++) {
        const int s = c * 64 + lane;
        int m;
        if (bytemode) m = ((const unsigned char*)maskv)[(size_t)b * 1024 + s];
        else          m = ((const int*)maskv)[(size_t)b * 1024 + s];
        const u64 bal = __ballot(m == 0);
        if (m == 0) {
            const int off = (int)__popcll(bal & ((1ull << lane) - 1ull));
            sidx[(size_t)b * 1024 + base + off] = s;
        }
        base += (int)__popcll(bal);
    }
    if (lane == 0) cnt[b] = base;
    for (int j = base + lane; j < 1024; j += 64) sidx[(size_t)b * 1024 + j] = 0;
}

// ---------------- gather-convert compacted enc rows to bf16, swizzled ----------------
__global__ __launch_bounds__(256) void conv_k(const float* __restrict__ enc,
                                              const int* __restrict__ sidx,
                                              const int* __restrict__ cnt,
                                              u16* __restrict__ encC) {
    const int j = blockIdx.x, b = blockIdx.y, t = threadIdx.x;
    const int c = cnt[b];
    if (j >= ((c + 127) & ~127)) return;
    const int s = (j < c) ? sidx[(size_t)b * 1024 + j] : 0;
    const float4 v = ((const float4*)(enc + ((size_t)s * 32 + b) * 1024))[t];
    const int gc = t >> 1, h = t & 1;                  // 16B chunk, half
    const int p = (gc & ~7) | ((gc & 7) ^ (j & 7));    // swizzle within K-segment
    uint2 o; o.x = pk2(v.x, v.y); o.y = pk2(v.z, v.w);
    *(uint2*)(encC + ((size_t)b * 1024 + j) * 1024 + p * 8 + h * 4) = o;
}

// ---------------- GEMM: T2 swizzled LDS + T3-minimal 2-phase dbuf ----------------
// 512 threads = 8 waves (wr 0..1 x wc 0..3); per-wave out 64x64 (acc[4][4]).
__global__ __launch_bounds__(512, 2) void gemm_r(
    const u16* __restrict__ encC,       // [32][1024][1024] bf16, swizzled
    const u16* __restrict__ Wb,         // [1024][1024] bf16, swizzled
    const int* __restrict__ sidx,
    const int* __restrict__ cnt,
    const float* __restrict__ hv,
    const float* __restrict__ W2,
    float*      __restrict__ scores)    // [32][1024] f32, pre-zeroed, atomics
{
    __shared__ u16 As[2][BM * BK];      // 2 x 16KB
    __shared__ u16 Bs[2][BN * BK];      // 2 x 32KB   (total 96KB)

    const int tid = threadIdx.x;
    const int bid = blockIdx.x;
    // XCD swizzle: 4 n-tiles of one m-strip contiguous on one XCD
    const int xcd = bid & 7, slot = bid >> 3;          // slot 0..127
    const int mstrip = xcd * 32 + (slot >> 2);         // 0..255
    const int nt = slot & 3;
    const int b = mstrip >> 3, mtile = mstrip & 7;
    const int c = cnt[b];
    if (mtile * 128 >= c) return;

    // staging geometry (linear LDS; sources pre-swizzled)
    const int arow = tid >> 3, acol = tid & 7;                 // A: 1024 chunks, j=0..1
    const u16* abase = encC + ((size_t)b * 1024 + mtile * 128) * 1024;
    const u16* bbase = Wb + (size_t)(nt * BN) * 1024;

    const int wid = tid >> 6, lane = tid & 63;
    const int wr = wid >> 2, wc = wid & 3;
    const int lhi = lane >> 4, llo = lane & 15;

    f32x4 acc[4][4] = {};

#define STAGE(BUF, KT)                                                          \
    {                                                                           \
        const size_t ko = (size_t)(KT) * 64;                                    \
        _Pragma("unroll")                                                       \
        for (int j = 0; j < 2; j++) {                                           \
            const int cix = j * 512 + tid;                                      \
            gload_lds16(abase + (size_t)(arow + j * 64) * 1024 + ko + acol * 8, \
                        &As[BUF][cix * 8]);                                     \
        }                                                                       \
        _Pragma("unroll")                                                       \
        for (int j = 0; j < 4; j++) {                                           \
            const int cix = j * 512 + tid;                                      \
            gload_lds16(bbase + (size_t)(arow + j * 64) * 1024 + ko + acol * 8, \
                        &Bs[BUF][cix * 8]);                                     \
        }                                                                       \
    }

#define COMPUTE(BUF)                                                            \
    {                                                                           \
        _Pragma("unroll")                                                       \
        for (int kk = 0; kk < 2; kk++) {                                        \
            s16x8 af[4], bfr[4];                                                \
            _Pragma("unroll")                                                   \
            for (int f = 0; f < 4; f++) {                                       \
                const int row = wr * 64 + f * 16 + llo;                         \
                const int ph = (kk * 4 + lhi) ^ (llo & 7);                      \
                af[f] = *(const s16x8*)&As[BUF][row * BK + ph * 8];             \
            }                                                                   \
            _Pragma("unroll")                                                   \
            for (int f = 0; f < 4; f++) {                                       \
                const int row = wc * 64 + f * 16 + llo;                         \
                const int ph = (kk * 4 + lhi) ^ (llo & 7);                      \
                bfr[f] = *(const s16x8*)&Bs[BUF][row * BK + ph * 8];            \
            }                                                                   \
            _Pragma("unroll")                                                   \
            for (int fi = 0; fi < 4; fi++)                                      \
                _Pragma("unroll")                                               \
                for (int fj = 0; fj < 4; fj++)                                  \
                    acc[fi][fj] = __builtin_amdgcn_mfma_f32_16x16x32_bf16(      \
                        af[fi], bfr[fj], acc[fi][fj], 0, 0, 0);                 \
        }                                                                       \
    }

    // prologue
    STAGE(0, 0);
    asm volatile("s_waitcnt vmcnt(0)" ::: "memory");
    __builtin_amdgcn_s_barrier();

    int buf = 0;
    for (int kt = 0; kt < 16; kt++) {
        if (kt < 15) STAGE(buf ^ 1, kt + 1);           // issue next tile first
        COMPUTE(buf);                                   // ds_read (lgkm auto) + MFMA
        asm volatile("s_waitcnt vmcnt(0)" ::: "memory");
        __builtin_amdgcn_s_barrier();
        buf ^= 1;
    }
#undef STAGE
#undef COMPUTE

    // epilogue: tanh(acc + hv) · w2, reduce over 16 llo-cols x 4 fj, scatter-atomic
    const float* hvb = hv + (size_t)b * 1024;
    float hvv[4], w2v[4];
#pragma unroll
    for (int fj = 0; fj < 4; fj++) {
        const int n = nt * BN + wc * 64 + fj * 16 + llo;
        hvv[fj] = hvb[n];
        w2v[fj] = W2[n];
    }
#pragma unroll
    for (int fi = 0; fi < 4; fi++) {
#pragma unroll
        for (int r = 0; r < 4; r++) {
            float sum = 0.f;
#pragma unroll
            for (int fj = 0; fj < 4; fj++) {
                const float x = acc[fi][fj][r] + hvv[fj];
                const float e = __expf(2.f * x);
                const float t = 1.f - 2.f / (e + 1.f);   // tanh(x)
                sum = fmaf(t, w2v[fj], sum);
            }
            sum += __shfl_xor(sum, 1);
            sum += __shfl_xor(sum, 2);
            sum += __shfl_xor(sum, 4);
            sum += __shfl_xor(sum, 8);
            if (llo == 0) {
                const int j = mtile * 128 + wr * 64 + fi * 16 + lhi * 4 + r;
                if (j < c) {
                    const int s = sidx[(size_t)b * 1024 + j];
                    atomicAdd(&scores[(size_t)b * 1024 + s], sum);
                }
            }
        }
    }
}

// ---------------- masked softmax per row b, mask dtype auto-detected ----------------
__global__ __launch_bounds__(256) void softmax_k(const float* __restrict__ scores,
                                                 const void* __restrict__ maskv,
                                                 float* __restrict__ out) {
    const int b = blockIdx.x, t = threadIdx.x;
    const int wid = t >> 6, lane = t & 63;
    const u32* mw = (const u32*)maskv;
    int f = 0;
#pragma unroll
    for (int j = 0; j < 32; j++) f |= (mw[t * 32 + j] > 1u) ? 1 : 0;
    __shared__ int sflag[4];
    const int anyf = __any(f);
    if (lane == 0) sflag[wid] = anyf;
    __syncthreads();
    const int bytemode = sflag[0] | sflag[1] | sflag[2] | sflag[3];

    int m0, m1, m2, m3;
    if (bytemode) {
        const uchar4 mk = ((const uchar4*)((const unsigned char*)maskv + (size_t)b * 1024))[t];
        m0 = mk.x; m1 = mk.y; m2 = mk.z; m3 = mk.w;
    } else {
        const int4 mk = ((const int4*)((const int*)maskv + (size_t)b * 1024))[t];
        m0 = mk.x; m1 = mk.y; m2 = mk.z; m3 = mk.w;
    }
    const float4 sc = ((const float4*)(scores + (size_t)b * 1024))[t];
    const float v0 = m0 ? -1e30f : sc.x;
    const float v1 = m1 ? -1e30f : sc.y;
    const float v2 = m2 ? -1e30f : sc.z;
    const float v3 = m3 ? -1e30f : sc.w;
    float mx = fmaxf(fmaxf(v0, v1), fmaxf(v2, v3));
#pragma unroll
    for (int off = 1; off < 64; off <<= 1) mx = fmaxf(mx, __shfl_xor(mx, off));
    __shared__ float redm[4], reds[4];
    if (lane == 0) redm[wid] = mx;
    __syncthreads();
    mx = fmaxf(fmaxf(redm[0], redm[1]), fmaxf(redm[2], redm[3]));
    const float e0 = m0 ? 0.f : __expf(v0 - mx);
    const float e1 = m1 ? 0.f : __expf(v1 - mx);
    const float e2 = m2 ? 0.f : __expf(v2 - mx);
    const float e3 = m3 ? 0.f : __expf(v3 - mx);
    float s = e0 + e1 + e2 + e3;
#pragma unroll
    for (int off = 1; off < 64; off <<= 1) s += __shfl_xor(s, off);
    if (lane == 0) reds[wid] = s;
    __syncthreads();
    s = reds[0] + reds[1] + reds[2] + reds[3];
    const float inv = 1.f / s;
    float4 o; o.x = e0 * inv; o.y = e1 * inv; o.z = e2 * inv; o.w = e3 * inv;
    ((float4*)(out + (size_t)b * 1024))[t] = o;
}

extern "C" void kernel_launch(void* const* d_in, const int* in_sizes, int n_in,
                              void* d_out, int out_size, void* d_ws, size_t ws_size,
                              hipStream_t stream) {
    const float* hidden = (const float*)d_in[0];
    const float* enc    = (const float*)d_in[1];           // (S,B,H_IN) f32
    const void*  mask   = d_in[2];
    const float* W1 = (const float*)d_in[3];               // (H, H_IN+H) f32
    const float* b1 = (const float*)d_in[4];
    const float* W2 = (const float*)d_in[5];
    float* out = (float*)d_out;

    char* ws = (char*)d_ws;
    float* ws_scores = (float*)ws;                          // 128 KB
    float* ws_hv     = (float*)(ws + (128u << 10));         // 128 KB
    u16*   ws_Wb     = (u16*)(ws + (256u << 10));           // 2 MB
    int*   ws_cnt    = (int*)(ws + (2304u << 10));          // 128 B
    int*   ws_sidx   = (int*)(ws + (2432u << 10));          // 128 KB
    u16*   ws_encC   = (u16*)(ws + (4096u << 10));          // 64 MB

    hipMemsetAsync(ws_scores, 0, 32768 * sizeof(float), stream);
    pack_k<<<512, 256, 0, stream>>>(W1, ws_Wb);
    hv_k<<<256, 256, 0, stream>>>(hidden, W1, b1, ws_hv);
    idx_k<<<8, 256, 0, stream>>>(mask, ws_sidx, ws_cnt);
    conv_k<<<dim3(1024, 32), 256, 0, stream>>>(enc, ws_sidx, ws_cnt, ws_encC);
    gemm_r<<<1024, 512, 0, stream>>>(ws_encC, ws_Wb, ws_sidx, ws_cnt, ws_hv, W2, ws_scores);
    softmax_k<<<32, 256, 0, stream>>>(ws_scores, mask, out);
}

// Round 5
// 135.422 us; speedup vs baseline: 1.0654x; 1.0654x over previous
//
#include <hip/hip_runtime.h>
#include <hip/hip_bf16.h>
#include <cstdint>

// Problem: B=32, S=1024, H_IN=1024, H=1024
// scores[b,s] = sum_h tanh( enc[b,s,:]·W1_enc[h,:] + hidden[b,:]·W1_hid[h,:] + b1[h] ) * W2[h]
// out[b,0,s] = softmax_s( mask ? -inf : scores )    (b2 is softmax-shift-invariant)
//
// Pipeline (4 launches): prep_k (pack W1_enc bf16 pre-swizzled + hv + mask compaction
// + zero scores) -> conv_k (gather enc rows -> bf16, pre-swizzled, 256-padded) ->
// gemm8 (256x256 tile, 8 waves, dbuf LDS, counted vmcnt(8), T2 swizzle, fused
// tanh·w2 epilogue) -> softmax_k.
//
// LDS swizzle (T2, rule 21 both-sides): 16B chunk c of row r lives at physical
// c^(r&7) within each 8-chunk K-segment. Sources stored pre-swizzled,
// global_load_lds stays linear, ds_read applies the XOR.

#define BM 256
#define BN 256
#define BK 64
#define NKT 16

typedef short  s16x8 __attribute__((ext_vector_type(8)));
typedef float  f32x4 __attribute__((ext_vector_type(4)));
typedef unsigned int u32;
typedef unsigned short u16;
typedef unsigned long long u64;

__device__ static inline u32 f2bf(float f) {            // f32 -> bf16 (RNE)
    u32 u = __float_as_uint(f);
    return (u + 0x7fffu + ((u >> 16) & 1u)) >> 16;
}
__device__ static inline u32 pk2(float a, float b) {
    return f2bf(a) | (f2bf(b) << 16);
}

__device__ static inline void gload_lds16(const void* g, void* l) {
    __builtin_amdgcn_global_load_lds(
        (const __attribute__((address_space(1))) u32*)g,
        (__attribute__((address_space(3))) u32*)l, 16, 0, 0);
}

// ---------------- prep: pack W1_enc (swizzled) + hv + mask compaction + zero scores ----------------
__global__ __launch_bounds__(256) void prep_k(const float* __restrict__ W1,
                                              const float* __restrict__ hidden,
                                              const float* __restrict__ b1,
                                              const void*  __restrict__ maskv,
                                              u16*   __restrict__ Wb,
                                              float* __restrict__ hv,
                                              int*   __restrict__ sidx,
                                              int*   __restrict__ cnt,
                                              float* __restrict__ scores) {
    const int bx = blockIdx.x, t = threadIdx.x;
    const int wid = t >> 6, lane = t & 63;
    __shared__ int sflag[4];

    if (bx < 512) {
        // pack W1_enc to bf16, swizzled: chunk gc -> (gc&~7)|((gc&7)^(n&7))
        const int i = bx * 256 + t;                    // 16B-out-chunk id, 0..131071
        const int n = i >> 7, gc = i & 127;
        const int p = (gc & ~7) | ((gc & 7) ^ (n & 7));
        const float4 v0 = *(const float4*)(W1 + (size_t)n * 2048 + gc * 8);
        const float4 v1 = *(const float4*)(W1 + (size_t)n * 2048 + gc * 8 + 4);
        uint4 o; o.x = pk2(v0.x, v0.y); o.y = pk2(v0.z, v0.w);
        o.z = pk2(v1.x, v1.y); o.w = pk2(v1.z, v1.w);
        *(uint4*)(Wb + (size_t)n * 1024 + p * 8) = o;
    } else if (bx < 768) {
        // hv[b][h] = hidden[b,:]·W1_hid[h,:] + b1[h]
        const int h = (bx - 512) * 4 + wid;
        const float4* wrow = (const float4*)(W1 + (size_t)h * 2048 + 1024);
        float4 w[4];
#pragma unroll
        for (int q = 0; q < 4; q++) w[q] = wrow[lane + 64 * q];
        for (int b = 0; b < 32; b++) {
            const float4* hb = (const float4*)(hidden + (size_t)b * 1024);
            float p = 0.f;
#pragma unroll
            for (int q = 0; q < 4; q++) {
                float4 x = hb[lane + 64 * q];
                p = fmaf(w[q].x, x.x, fmaf(w[q].y, x.y, fmaf(w[q].z, x.z, fmaf(w[q].w, x.w, p))));
            }
#pragma unroll
            for (int off = 1; off < 64; off <<= 1) p += __shfl_xor(p, off);
            if (lane == 0) hv[(size_t)b * 1024 + h] = p + b1[h];
        }
    } else if (bx < 776) {
        // mask dtype detect + per-batch stable compaction of unmasked s
        const u32* mw = (const u32*)maskv;
        int f = 0;
#pragma unroll
        for (int j = 0; j < 32; j++) f |= (mw[t * 32 + j] > 1u) ? 1 : 0;
        const int anyf = __any(f);
        if (lane == 0) sflag[wid] = anyf;
        __syncthreads();
        const int bytemode = sflag[0] | sflag[1] | sflag[2] | sflag[3];

        const int b = (bx - 768) * 4 + wid;
        int base = 0;
        for (int c = 0; c < 16; c++) {
            const int s = c * 64 + lane;
            int m;
            if (bytemode) m = ((const unsigned char*)maskv)[(size_t)b * 1024 + s];
            else          m = ((const int*)maskv)[(size_t)b * 1024 + s];
            const u64 bal = __ballot(m == 0);
            if (m == 0) {
                const int off = (int)__popcll(bal & ((1ull << lane) - 1ull));
                sidx[(size_t)b * 1024 + base + off] = s;
            }
            base += (int)__popcll(bal);
        }
        if (lane == 0) cnt[b] = base;
        for (int j = base + lane; j < 1024; j += 64) sidx[(size_t)b * 1024 + j] = 0;
    } else {
        // zero scores: 32 blocks x 256 thr x float4 = 32768 floats
        const int i = (bx - 776) * 256 + t;
        ((float4*)scores)[i] = make_float4(0.f, 0.f, 0.f, 0.f);
    }
}

// ---------------- gather-convert compacted enc rows to bf16, swizzled, 256-padded ----------------
// grid (256, 32): block handles rows [bx*4, bx*4+4) of batch by
__global__ __launch_bounds__(256) void conv_k(const float* __restrict__ enc,
                                              const int* __restrict__ sidx,
                                              const int* __restrict__ cnt,
                                              u16* __restrict__ encC) {
    const int b = blockIdx.y, t = threadIdx.x;
    const int c = cnt[b];
    const int jmax = (c + 255) & ~255;                 // pad to BM=256 tiles
    const int j0 = blockIdx.x * 4;
    if (j0 >= jmax) return;
    const int gc = t >> 1, h = t & 1;                  // 16B chunk, half
#pragma unroll
    for (int r = 0; r < 4; r++) {
        const int j = j0 + r;
        const int s = (j < c) ? sidx[(size_t)b * 1024 + j] : 0;
        const float4 v = ((const float4*)(enc + ((size_t)s * 32 + b) * 1024))[t];
        const int p = (gc & ~7) | ((gc & 7) ^ (j & 7));
        uint2 o; o.x = pk2(v.x, v.y); o.y = pk2(v.z, v.w);
        *(uint2*)(encC + ((size_t)b * 1024 + j) * 1024 + p * 8 + h * 4) = o;
    }
}

// ---------------- GEMM: 256x256 tile, 8 waves, dbuf LDS, counted vmcnt, fused epilogue ----------------
// 512 threads = 8 waves (wr 0..1 x wc 0..3); per-wave out 128x64 (acc[8][4]).
__global__ __launch_bounds__(512, 2) void gemm8(
    const u16* __restrict__ encC,       // [32][1024][1024] bf16, swizzled rows
    const u16* __restrict__ Wb,         // [1024][1024] bf16, swizzled rows
    const int* __restrict__ sidx,
    const int* __restrict__ cnt,
    const float* __restrict__ hv,
    const float* __restrict__ W2,
    float*      __restrict__ scores)    // [32][1024] f32, pre-zeroed, atomics
{
    __shared__ u16 As[2][BM * BK];      // 2 x 32KB
    __shared__ u16 Bs[2][BN * BK];      // 2 x 32KB   (total 128KB)

    const int tid = threadIdx.x;
    const int bid = blockIdx.x;         // 512 blocks
    // XCD swizzle (bijective, 512 = 8*64): 4 nt of one (b,mt) strip stay on one XCD
    const int xcd = bid & 7, idx = bid >> 3;           // idx 0..63
    const int strip = xcd * 16 + (idx >> 2);           // 0..127 = b*4+mt
    const int nt = idx & 3;
    const int b = strip >> 2, mt = strip & 3;
    const int c = cnt[b];
    if (mt * BM >= c) return;

    const u16* abase = encC + ((size_t)b * 1024 + mt * BM) * 1024;
    const u16* bbase = Wb + (size_t)(nt * BN) * 1024;

    const int wid = tid >> 6, lane = tid & 63;
    const int wr = wid >> 2, wc = wid & 3;
    const int lhi = lane >> 4, llo = lane & 15;

    f32x4 acc[8][4] = {};

#define STAGE(BUF, KT)                                                           \
    {                                                                            \
        const size_t ko = (size_t)(KT) * 64;                                     \
        _Pragma("unroll")                                                        \
        for (int j = 0; j < 4; j++) {                                            \
            const int cix = j * 512 + tid;                                       \
            gload_lds16(abase + (size_t)(cix >> 3) * 1024 + ko + (cix & 7) * 8,  \
                        &As[BUF][cix * 8]);                                      \
        }                                                                        \
        _Pragma("unroll")                                                        \
        for (int j = 0; j < 4; j++) {                                            \
            const int cix = j * 512 + tid;                                       \
            gload_lds16(bbase + (size_t)(cix >> 3) * 1024 + ko + (cix & 7) * 8,  \
                        &Bs[BUF][cix * 8]);                                      \
        }                                                                        \
    }

#define COMPUTE(BUF)                                                             \
    {                                                                            \
        _Pragma("unroll")                                                        \
        for (int kk = 0; kk < 2; kk++) {                                         \
            s16x8 af[8], bfr[4];                                                 \
            _Pragma("unroll")                                                    \
            for (int f = 0; f < 8; f++) {                                        \
                const int row = wr * 128 + f * 16 + llo;                         \
                const int ph = (kk * 4 + lhi) ^ (llo & 7);                       \
                af[f] = *(const s16x8*)&As[BUF][row * BK + ph * 8];              \
            }                                                                    \
            _Pragma("unroll")                                                    \
            for (int f = 0; f < 4; f++) {                                        \
                const int row = wc * 64 + f * 16 + llo;                          \
                const int ph = (kk * 4 + lhi) ^ (llo & 7);                       \
                bfr[f] = *(const s16x8*)&Bs[BUF][row * BK + ph * 8];             \
            }                                                                    \
            _Pragma("unroll")                                                    \
            for (int fi = 0; fi < 8; fi++)                                       \
                _Pragma("unroll")                                                \
                for (int fj = 0; fj < 4; fj++)                                   \
                    acc[fi][fj] = __builtin_amdgcn_mfma_f32_16x16x32_bf16(       \
                        af[fi], bfr[fj], acc[fi][fj], 0, 0, 0);                  \
        }                                                                        \
    }

    // prologue
    STAGE(0, 0);

#pragma unroll 2
    for (int kt = 0; kt < NKT; kt++) {
        if (kt + 1 < NKT) {
            STAGE((kt + 1) & 1, kt + 1);               // issue next tile first
            // counted wait: drains stage(kt)'s 8 loads, leaves stage(kt+1)'s 8 in flight
            asm volatile("s_waitcnt vmcnt(8)" ::: "memory");
        } else {
            asm volatile("s_waitcnt vmcnt(0)" ::: "memory");
        }
        __builtin_amdgcn_s_barrier();                  // stage(kt) visible to all
        COMPUTE(kt & 1);
        asm volatile("s_waitcnt lgkmcnt(0)" ::: "memory");
        __builtin_amdgcn_s_barrier();                  // all done reading buf kt&1
    }
#undef STAGE
#undef COMPUTE

    // epilogue: tanh(acc + hv) · w2, reduce over 16 llo-cols x 4 fj, scatter-atomic
    const float* hvb = hv + (size_t)b * 1024;
    float hvv[4], w2v[4];
#pragma unroll
    for (int fj = 0; fj < 4; fj++) {
        const int n = nt * BN + wc * 64 + fj * 16 + llo;
        hvv[fj] = hvb[n];
        w2v[fj] = W2[n];
    }
#pragma unroll
    for (int fi = 0; fi < 8; fi++) {
#pragma unroll
        for (int r = 0; r < 4; r++) {
            float sum = 0.f;
#pragma unroll
            for (int fj = 0; fj < 4; fj++) {
                const float x = acc[fi][fj][r] + hvv[fj];
                const float e = __expf(2.f * x);
                const float t = 1.f - 2.f / (e + 1.f);   // tanh(x)
                sum = fmaf(t, w2v[fj], sum);
            }
            sum += __shfl_xor(sum, 1);
            sum += __shfl_xor(sum, 2);
            sum += __shfl_xor(sum, 4);
            sum += __shfl_xor(sum, 8);
            if (llo == 0) {
                const int j = mt * BM + wr * 128 + fi * 16 + lhi * 4 + r;
                if (j < c) {
                    const int s = sidx[(size_t)b * 1024 + j];
                    atomicAdd(&scores[(size_t)b * 1024 + s], sum);
                }
            }
        }
    }
}

// ---------------- masked softmax per row b, mask dtype auto-detected ----------------
__global__ __launch_bounds__(256) void softmax_k(const float* __restrict__ scores,
                                                 const void* __restrict__ maskv,
                                                 float* __restrict__ out) {
    const int b = blockIdx.x, t = threadIdx.x;
    const int wid = t >> 6, lane = t & 63;
    const u32* mw = (const u32*)maskv;
    int f = 0;
#pragma unroll
    for (int j = 0; j < 32; j++) f |= (mw[t * 32 + j] > 1u) ? 1 : 0;
    __shared__ int sflag[4];
    const int anyf = __any(f);
    if (lane == 0) sflag[wid] = anyf;
    __syncthreads();
    const int bytemode = sflag[0] | sflag[1] | sflag[2] | sflag[3];

    int m0, m1, m2, m3;
    if (bytemode) {
        const uchar4 mk = ((const uchar4*)((const unsigned char*)maskv + (size_t)b * 1024))[t];
        m0 = mk.x; m1 = mk.y; m2 = mk.z; m3 = mk.w;
    } else {
        const int4 mk = ((const int4*)((const int*)maskv + (size_t)b * 1024))[t];
        m0 = mk.x; m1 = mk.y; m2 = mk.z; m3 = mk.w;
    }
    const float4 sc = ((const float4*)(scores + (size_t)b * 1024))[t];
    const float v0 = m0 ? -1e30f : sc.x;
    const float v1 = m1 ? -1e30f : sc.y;
    const float v2 = m2 ? -1e30f : sc.z;
    const float v3 = m3 ? -1e30f : sc.w;
    float mx = fmaxf(fmaxf(v0, v1), fmaxf(v2, v3));
#pragma unroll
    for (int off = 1; off < 64; off <<= 1) mx = fmaxf(mx, __shfl_xor(mx, off));
    __shared__ float redm[4], reds[4];
    if (lane == 0) redm[wid] = mx;
    __syncthreads();
    mx = fmaxf(fmaxf(redm[0], redm[1]), fmaxf(redm[2], redm[3]));
    const float e0 = m0 ? 0.f : __expf(v0 - mx);
    const float e1 = m1 ? 0.f : __expf(v1 - mx);
    const float e2 = m2 ? 0.f : __expf(v2 - mx);
    const float e3 = m3 ? 0.f : __expf(v3 - mx);
    float s = e0 + e1 + e2 + e3;
#pragma unroll
    for (int off = 1; off < 64; off <<= 1) s += __shfl_xor(s, off);
    if (lane == 0) reds[wid] = s;
    __syncthreads();
    s = reds[0] + reds[1] + reds[2] + reds[3];
    const float inv = 1.f / s;
    float4 o; o.x = e0 * inv; o.y = e1 * inv; o.z = e2 * inv; o.w = e3 * inv;
    ((float4*)(out + (size_t)b * 1024))[t] = o;
}

extern "C" void kernel_launch(void* const* d_in, const int* in_sizes, int n_in,
                              void* d_out, int out_size, void* d_ws, size_t ws_size,
                              hipStream_t stream) {
    const float* hidden = (const float*)d_in[0];
    const float* enc    = (const float*)d_in[1];           // (S,B,H_IN) f32
    const void*  mask   = d_in[2];
    const float* W1 = (const float*)d_in[3];               // (H, H_IN+H) f32
    const float* b1 = (const float*)d_in[4];
    const float* W2 = (const float*)d_in[5];
    float* out = (float*)d_out;

    char* ws = (char*)d_ws;
    float* ws_scores = (float*)ws;                          // 128 KB
    float* ws_hv     = (float*)(ws + (128u << 10));         // 128 KB
    u16*   ws_Wb     = (u16*)(ws + (256u << 10));           // 2 MB
    int*   ws_cnt    = (int*)(ws + (2304u << 10));          // 128 B
    int*   ws_sidx   = (int*)(ws + (2432u << 10));          // 128 KB
    u16*   ws_encC   = (u16*)(ws + (4096u << 10));          // 64 MB

    prep_k<<<808, 256, 0, stream>>>(W1, hidden, b1, mask, ws_Wb, ws_hv, ws_sidx, ws_cnt, ws_scores);
    conv_k<<<dim3(256, 32), 256, 0, stream>>>(enc, ws_sidx, ws_cnt, ws_encC);
    gemm8<<<512, 512, 0, stream>>>(ws_encC, ws_Wb, ws_sidx, ws_cnt, ws_hv, W2, ws_scores);
    softmax_k<<<32, 256, 0, stream>>>(ws_scores, mask, out);
}

// Round 6
// 134.105 us; speedup vs baseline: 1.0759x; 1.0098x over previous
//
#include <hip/hip_runtime.h>
#include <hip/hip_bf16.h>
#include <cstdint>

// Problem: B=32, S=1024, H_IN=1024, H=1024
// scores[b,s] = sum_h tanh( enc[b,s,:]·W1_enc[h,:] + hidden[b,:]·W1_hid[h,:] + b1[h] ) * W2[h]
// out[b,0,s] = softmax_s( mask ? -inf : scores )    (b2 is softmax-shift-invariant)
//
// Pipeline (4 launches): prep_k (pack W1_enc bf16 pre-swizzled + hv + mask compaction
// + zero scores) -> conv_k (gather enc rows -> bf16, pre-swizzled, 256-padded) ->
// gemm3p (BM=256 BN=128 BK=64, 3-deep LDS pipeline, counted vmcnt(6) never 0,
// T2 swizzle, T5 setprio, fused tanh·w2 epilogue) -> softmax_k.
//
// vmcnt ledger (6 loads/thread per stage): at step t entry, tiles {t+1} outstanding
// (t was drained by step t-1's vmcnt(6)). Issue STAGE(t+2) -> {t+1,t+2}=12 out.
// After MFMA: vmcnt(6) drains t+1, leaves t+2 in flight across the barrier.
// Buffer t%3: stage(t+2) targets (t+2)%3 whose previous tile (t-1) was released
// at end of step t-1 (lgkm0 + s_barrier).

#define BM 256
#define BN 128
#define BK 64
#define NKT 16

typedef short  s16x8 __attribute__((ext_vector_type(8)));
typedef float  f32x4 __attribute__((ext_vector_type(4)));
typedef unsigned int u32;
typedef unsigned short u16;
typedef unsigned long long u64;

__device__ static inline u32 f2bf(float f) {            // f32 -> bf16 (RNE)
    u32 u = __float_as_uint(f);
    return (u + 0x7fffu + ((u >> 16) & 1u)) >> 16;
}
__device__ static inline u32 pk2(float a, float b) {
    return f2bf(a) | (f2bf(b) << 16);
}

__device__ static inline void gload_lds16(const void* g, void* l) {
    __builtin_amdgcn_global_load_lds(
        (const __attribute__((address_space(1))) u32*)g,
        (__attribute__((address_space(3))) u32*)l, 16, 0, 0);
}

// ---------------- prep: pack W1_enc (swizzled) + hv + mask compaction + zero scores ----------------
__global__ __launch_bounds__(256) void prep_k(const float* __restrict__ W1,
                                              const float* __restrict__ hidden,
                                              const float* __restrict__ b1,
                                              const void*  __restrict__ maskv,
                                              u16*   __restrict__ Wb,
                                              float* __restrict__ hv,
                                              int*   __restrict__ sidx,
                                              int*   __restrict__ cnt,
                                              float* __restrict__ scores) {
    const int bx = blockIdx.x, t = threadIdx.x;
    const int wid = t >> 6, lane = t & 63;
    __shared__ int sflag[4];

    if (bx < 512) {
        // pack W1_enc to bf16, swizzled: chunk gc -> (gc&~7)|((gc&7)^(n&7))
        const int i = bx * 256 + t;                    // 16B-out-chunk id, 0..131071
        const int n = i >> 7, gc = i & 127;
        const int p = (gc & ~7) | ((gc & 7) ^ (n & 7));
        const float4 v0 = *(const float4*)(W1 + (size_t)n * 2048 + gc * 8);
        const float4 v1 = *(const float4*)(W1 + (size_t)n * 2048 + gc * 8 + 4);
        uint4 o; o.x = pk2(v0.x, v0.y); o.y = pk2(v0.z, v0.w);
        o.z = pk2(v1.x, v1.y); o.w = pk2(v1.z, v1.w);
        *(uint4*)(Wb + (size_t)n * 1024 + p * 8) = o;
    } else if (bx < 768) {
        // hv[b][h] = hidden[b,:]·W1_hid[h,:] + b1[h]
        const int h = (bx - 512) * 4 + wid;
        const float4* wrow = (const float4*)(W1 + (size_t)h * 2048 + 1024);
        float4 w[4];
#pragma unroll
        for (int q = 0; q < 4; q++) w[q] = wrow[lane + 64 * q];
        for (int b = 0; b < 32; b++) {
            const float4* hb = (const float4*)(hidden + (size_t)b * 1024);
            float p = 0.f;
#pragma unroll
            for (int q = 0; q < 4; q++) {
                float4 x = hb[lane + 64 * q];
                p = fmaf(w[q].x, x.x, fmaf(w[q].y, x.y, fmaf(w[q].z, x.z, fmaf(w[q].w, x.w, p))));
            }
#pragma unroll
            for (int off = 1; off < 64; off <<= 1) p += __shfl_xor(p, off);
            if (lane == 0) hv[(size_t)b * 1024 + h] = p + b1[h];
        }
    } else if (bx < 776) {
        // mask dtype detect + per-batch stable compaction of unmasked s
        const u32* mw = (const u32*)maskv;
        int f = 0;
#pragma unroll
        for (int j = 0; j < 32; j++) f |= (mw[t * 32 + j] > 1u) ? 1 : 0;
        const int anyf = __any(f);
        if (lane == 0) sflag[wid] = anyf;
        __syncthreads();
        const int bytemode = sflag[0] | sflag[1] | sflag[2] | sflag[3];

        const int b = (bx - 768) * 4 + wid;
        int base = 0;
        for (int c = 0; c < 16; c++) {
            const int s = c * 64 + lane;
            int m;
            if (bytemode) m = ((const unsigned char*)maskv)[(size_t)b * 1024 + s];
            else          m = ((const int*)maskv)[(size_t)b * 1024 + s];
            const u64 bal = __ballot(m == 0);
            if (m == 0) {
                const int off = (int)__popcll(bal & ((1ull << lane) - 1ull));
                sidx[(size_t)b * 1024 + base + off] = s;
            }
            base += (int)__popcll(bal);
        }
        if (lane == 0) cnt[b] = base;
        for (int j = base + lane; j < 1024; j += 64) sidx[(size_t)b * 1024 + j] = 0;
    } else {
        // zero scores: 32 blocks x 256 thr x float4 = 32768 floats
        const int i = (bx - 776) * 256 + t;
        ((float4*)scores)[i] = make_float4(0.f, 0.f, 0.f, 0.f);
    }
}

// ---------------- gather-convert compacted enc rows to bf16, swizzled, 256-padded ----------------
__global__ __launch_bounds__(256) void conv_k(const float* __restrict__ enc,
                                              const int* __restrict__ sidx,
                                              const int* __restrict__ cnt,
                                              u16* __restrict__ encC) {
    const int b = blockIdx.y, t = threadIdx.x;
    const int c = cnt[b];
    const int jmax = (c + 255) & ~255;                 // pad to BM=256 tiles
    const int j0 = blockIdx.x * 4;
    if (j0 >= jmax) return;
    const int gc = t >> 1, h = t & 1;                  // 16B chunk, half
#pragma unroll
    for (int r = 0; r < 4; r++) {
        const int j = j0 + r;
        const int s = (j < c) ? sidx[(size_t)b * 1024 + j] : 0;
        const float4 v = ((const float4*)(enc + ((size_t)s * 32 + b) * 1024))[t];
        const int p = (gc & ~7) | ((gc & 7) ^ (j & 7));
        uint2 o; o.x = pk2(v.x, v.y); o.y = pk2(v.z, v.w);
        *(uint2*)(encC + ((size_t)b * 1024 + j) * 1024 + p * 8 + h * 4) = o;
    }
}

// ---------------- GEMM: 3-deep LDS pipeline, counted vmcnt, fused epilogue ----------------
// 512 threads = 8 waves (wr 0..3 x wc 0..1); per-wave out 64x64 (acc[4][4]).
__global__ __launch_bounds__(512, 2) void gemm3p(
    const u16* __restrict__ encC,       // [32][1024][1024] bf16, swizzled rows
    const u16* __restrict__ Wb,         // [1024][1024] bf16, swizzled rows
    const int* __restrict__ sidx,
    const int* __restrict__ cnt,
    const float* __restrict__ hv,
    const float* __restrict__ W2,
    float*      __restrict__ scores)    // [32][1024] f32, pre-zeroed, atomics
{
    __shared__ u16 As[3][BM * BK];      // 3 x 32KB
    __shared__ u16 Bs[3][BN * BK];      // 3 x 16KB   (total 144KB)

    const int tid = threadIdx.x;
    const int bid = blockIdx.x;         // 1024 blocks
    // XCD swizzle (bijective, 1024 = 8*128): 8 nt of one (b,mt) strip stay on one XCD
    const int xcd = bid & 7, idx = bid >> 3;           // idx 0..127
    const int strip = xcd * 16 + (idx >> 3);           // 0..127 = b*4+mt
    const int nt = idx & 7;
    const int b = strip >> 2, mt = strip & 3;
    const int c = cnt[b];
    if (mt * BM >= c) return;

    const u16* abase = encC + ((size_t)b * 1024 + mt * BM) * 1024;
    const u16* bbase = Wb + (size_t)(nt * BN) * 1024;

    const int wid = tid >> 6, lane = tid & 63;
    const int wr = wid & 3, wc = wid >> 2;
    const int lhi = lane >> 4, llo = lane & 15;

    f32x4 acc[4][4] = {};

#define STAGE(BUF, KT)                                                           \
    {                                                                            \
        const size_t ko = (size_t)(KT) * 64;                                     \
        _Pragma("unroll")                                                        \
        for (int j = 0; j < 4; j++) {                                            \
            const int cix = j * 512 + tid;                                       \
            gload_lds16(abase + (size_t)(cix >> 3) * 1024 + ko + (cix & 7) * 8,  \
                        &As[BUF][cix * 8]);                                      \
        }                                                                        \
        _Pragma("unroll")                                                        \
        for (int j = 0; j < 2; j++) {                                            \
            const int cix = j * 512 + tid;                                       \
            gload_lds16(bbase + (size_t)(cix >> 3) * 1024 + ko + (cix & 7) * 8,  \
                        &Bs[BUF][cix * 8]);                                      \
        }                                                                        \
    }

#define COMPUTE(BUF)                                                             \
    {                                                                            \
        s16x8 af[2][4], bfr[2][4];                                               \
        _Pragma("unroll")                                                        \
        for (int kk = 0; kk < 2; kk++) {                                         \
            _Pragma("unroll")                                                    \
            for (int f = 0; f < 4; f++) {                                        \
                const int row = wr * 64 + f * 16 + llo;                          \
                const int ph = (kk * 4 + lhi) ^ (llo & 7);                       \
                af[kk][f] = *(const s16x8*)&As[BUF][row * BK + ph * 8];          \
            }                                                                    \
            _Pragma("unroll")                                                    \
            for (int f = 0; f < 4; f++) {                                        \
                const int row = wc * 64 + f * 16 + llo;                          \
                const int ph = (kk * 4 + lhi) ^ (llo & 7);                       \
                bfr[kk][f] = *(const s16x8*)&Bs[BUF][row * BK + ph * 8];         \
            }                                                                    \
        }                                                                        \
        __builtin_amdgcn_s_setprio(1);                                           \
        _Pragma("unroll")                                                        \
        for (int kk = 0; kk < 2; kk++)                                           \
            _Pragma("unroll")                                                    \
            for (int fi = 0; fi < 4; fi++)                                       \
                _Pragma("unroll")                                                \
                for (int fj = 0; fj < 4; fj++)                                   \
                    acc[fi][fj] = __builtin_amdgcn_mfma_f32_16x16x32_bf16(       \
                        af[kk][fi], bfr[kk][fj], acc[fi][fj], 0, 0, 0);          \
        __builtin_amdgcn_s_setprio(0);                                           \
    }

    // prologue: stage tiles 0,1; drain tile 0 (leave tile 1 in flight)
    STAGE(0, 0);
    STAGE(1, 1);
    asm volatile("s_waitcnt vmcnt(6)" ::: "memory");
    __builtin_amdgcn_s_barrier();

    int cur = 0;                                        // t % 3
    for (int t = 0; t < NKT - 2; t++) {
        const int sb = (cur == 0) ? 2 : cur - 1;        // (t+2) % 3
        STAGE(sb, t + 2);                               // buffer released end of step t-1
        COMPUTE(cur);                                   // tile t (drained at step t-1)
        asm volatile("s_waitcnt vmcnt(6)" ::: "memory");  // drain tile t+1; t+2 stays in flight
        asm volatile("s_waitcnt lgkmcnt(0)" ::: "memory");
        __builtin_amdgcn_s_barrier();                   // all waves done reading tile t
        cur = (cur == 2) ? 0 : cur + 1;
    }
    // t = NKT-2: nothing to stage; drain last tile for next step
    COMPUTE(cur);
    asm volatile("s_waitcnt vmcnt(0)" ::: "memory");
    asm volatile("s_waitcnt lgkmcnt(0)" ::: "memory");
    __builtin_amdgcn_s_barrier();
    cur = (cur == 2) ? 0 : cur + 1;
    // t = NKT-1: final compute, no sync needed after
    COMPUTE(cur);
#undef STAGE
#undef COMPUTE

    // epilogue: tanh(acc + hv) · w2, reduce over 16 llo-cols x 4 fj, scatter-atomic
    const float* hvb = hv + (size_t)b * 1024;
    float hvv[4], w2v[4];
#pragma unroll
    for (int fj = 0; fj < 4; fj++) {
        const int n = nt * BN + wc * 64 + fj * 16 + llo;
        hvv[fj] = hvb[n];
        w2v[fj] = W2[n];
    }
#pragma unroll
    for (int fi = 0; fi < 4; fi++) {
#pragma unroll
        for (int r = 0; r < 4; r++) {
            float sum = 0.f;
#pragma unroll
            for (int fj = 0; fj < 4; fj++) {
                const float x = acc[fi][fj][r] + hvv[fj];
                const float e = __expf(2.f * x);
                const float t = 1.f - 2.f / (e + 1.f);   // tanh(x)
                sum = fmaf(t, w2v[fj], sum);
            }
            sum += __shfl_xor(sum, 1);
            sum += __shfl_xor(sum, 2);
            sum += __shfl_xor(sum, 4);
            sum += __shfl_xor(sum, 8);
            if (llo == 0) {
                const int j = mt * BM + wr * 64 + fi * 16 + lhi * 4 + r;
                if (j < c) {
                    const int s = sidx[(size_t)b * 1024 + j];
                    atomicAdd(&scores[(size_t)b * 1024 + s], sum);
                }
            }
        }
    }
}

// ---------------- masked softmax per row b, mask dtype auto-detected ----------------
__global__ __launch_bounds__(256) void softmax_k(const float* __restrict__ scores,
                                                 const void* __restrict__ maskv,
                                                 float* __restrict__ out) {
    const int b = blockIdx.x, t = threadIdx.x;
    const int wid = t >> 6, lane = t & 63;
    const u32* mw = (const u32*)maskv;
    int f = 0;
#pragma unroll
    for (int j = 0; j < 32; j++) f |= (mw[t * 32 + j] > 1u) ? 1 : 0;
    __shared__ int sflag[4];
    const int anyf = __any(f);
    if (lane == 0) sflag[wid] = anyf;
    __syncthreads();
    const int bytemode = sflag[0] | sflag[1] | sflag[2] | sflag[3];

    int m0, m1, m2, m3;
    if (bytemode) {
        const uchar4 mk = ((const uchar4*)((const unsigned char*)maskv + (size_t)b * 1024))[t];
        m0 = mk.x; m1 = mk.y; m2 = mk.z; m3 = mk.w;
    } else {
        const int4 mk = ((const int4*)((const int*)maskv + (size_t)b * 1024))[t];
        m0 = mk.x; m1 = mk.y; m2 = mk.z; m3 = mk.w;
    }
    const float4 sc = ((const float4*)(scores + (size_t)b * 1024))[t];
    const float v0 = m0 ? -1e30f : sc.x;
    const float v1 = m1 ? -1e30f : sc.y;
    const float v2 = m2 ? -1e30f : sc.z;
    const float v3 = m3 ? -1e30f : sc.w;
    float mx = fmaxf(fmaxf(v0, v1), fmaxf(v2, v3));
#pragma unroll
    for (int off = 1; off < 64; off <<= 1) mx = fmaxf(mx, __shfl_xor(mx, off));
    __shared__ float redm[4], reds[4];
    if (lane == 0) redm[wid] = mx;
    __syncthreads();
    mx = fmaxf(fmaxf(redm[0], redm[1]), fmaxf(redm[2], redm[3]));
    const float e0 = m0 ? 0.f : __expf(v0 - mx);
    const float e1 = m1 ? 0.f : __expf(v1 - mx);
    const float e2 = m2 ? 0.f : __expf(v2 - mx);
    const float e3 = m3 ? 0.f : __expf(v3 - mx);
    float s = e0 + e1 + e2 + e3;
#pragma unroll
    for (int off = 1; off < 64; off <<= 1) s += __shfl_xor(s, off);
    if (lane == 0) reds[wid] = s;
    __syncthreads();
    s = reds[0] + reds[1] + reds[2] + reds[3];
    const float inv = 1.f / s;
    float4 o; o.x = e0 * inv; o.y = e1 * inv; o.z = e2 * inv; o.w = e3 * inv;
    ((float4*)(out + (size_t)b * 1024))[t] = o;
}

extern "C" void kernel_launch(void* const* d_in, const int* in_sizes, int n_in,
                              void* d_out, int out_size, void* d_ws, size_t ws_size,
                              hipStream_t stream) {
    const float* hidden = (const float*)d_in[0];
    const float* enc    = (const float*)d_in[1];           // (S,B,H_IN) f32
    const void*  mask   = d_in[2];
    const float* W1 = (const float*)d_in[3];               // (H, H_IN+H) f32
    const float* b1 = (const float*)d_in[4];
    const float* W2 = (const float*)d_in[5];
    float* out = (float*)d_out;

    char* ws = (char*)d_ws;
    float* ws_scores = (float*)ws;                          // 128 KB
    float* ws_hv     = (float*)(ws + (128u << 10));         // 128 KB
    u16*   ws_Wb     = (u16*)(ws + (256u << 10));           // 2 MB
    int*   ws_cnt    = (int*)(ws + (2304u << 10));          // 128 B
    int*   ws_sidx   = (int*)(ws + (2432u << 10));          // 128 KB
    u16*   ws_encC   = (u16*)(ws + (4096u << 10));          // 64 MB

    prep_k<<<808, 256, 0, stream>>>(W1, hidden, b1, mask, ws_Wb, ws_hv, ws_sidx, ws_cnt, ws_scores);
    conv_k<<<dim3(256, 32), 256, 0, stream>>>(enc, ws_sidx, ws_cnt, ws_encC);
    gemm3p<<<1024, 512, 0, stream>>>(ws_encC, ws_Wb, ws_sidx, ws_cnt, ws_hv, W2, ws_scores);
    softmax_k<<<32, 256, 0, stream>>>(ws_scores, mask, out);
}